// Round 2
// baseline (328.559 us; speedup 1.0000x reference)
//
#include <hip/hip_runtime.h>

// Sizes for this problem (fixed): B=2, C=256, H=W=64, P=3 -> Hp=Wp=62, Np=3844
// X correlation grid: 4096 x 4096 fp32 = 64 MiB (reused across batches)

// ---------------------------------------------------------------------------
// Kernel 1: per-pixel channel L2 normalization for both maps, both batches.
__global__ void norm_kernel(const float* __restrict__ df1, const float* __restrict__ df2,
                            float* __restrict__ Bn, float* __restrict__ An) {
  int t = blockIdx.x * blockDim.x + threadIdx.x;   // 0 .. 16383
  int pix = t & 4095;
  int bm = t >> 12;            // 0..3
  int b = bm >> 1, m = bm & 1; // m=0 -> df1 (input, B), m=1 -> df2 (ref, A)
  const float* src = (m == 0 ? df1 : df2) + (size_t)b * 256 * 4096 + pix;
  float* dst = (m == 0 ? Bn : An) + (size_t)b * 256 * 4096 + pix;
  float ss = 0.f;
  for (int c = 0; c < 256; ++c) {
    float v = src[(size_t)c * 4096];
    ss += v * v;
  }
  float n = sqrtf(ss);
  float scale = 1.f / fmaxf(n, 1e-12f);
  for (int c = 0; c < 256; ++c) dst[(size_t)c * 4096] = src[(size_t)c * 4096] * scale;
}

// ---------------------------------------------------------------------------
// Kernel 2: X = A^T B  (per batch).  A,B are (256, 4096) row-major (c-major).
// X[u][v] = sum_c A[c][u] * B[c][v].  128x128 tile, 256 threads, 8x8 micro.
__global__ __launch_bounds__(256) void gemm128(const float* __restrict__ A,
                                               const float* __restrict__ B,
                                               float* __restrict__ X) {
  __shared__ __align__(16) float As[16][128];
  __shared__ __align__(16) float Bs[16][128];
  const int tid = threadIdx.x;
  const int tx = tid & 15, ty = tid >> 4;
  const int u0 = blockIdx.y << 7, v0 = blockIdx.x << 7;
  const int lr = tid >> 5;            // 0..7
  const int lc = (tid & 31) << 2;     // 0..124 step 4
  float acc[8][8];
#pragma unroll
  for (int i = 0; i < 8; ++i)
#pragma unroll
    for (int j = 0; j < 8; ++j) acc[i][j] = 0.f;

  const float* Abase = A + (size_t)lr * 4096 + u0 + lc;
  const float* Bbase = B + (size_t)lr * 4096 + v0 + lc;

  for (int k0 = 0; k0 < 256; k0 += 16) {
    float4 a0 = *(const float4*)(Abase + (size_t)k0 * 4096);
    float4 a1 = *(const float4*)(Abase + (size_t)(k0 + 8) * 4096);
    float4 b0 = *(const float4*)(Bbase + (size_t)k0 * 4096);
    float4 b1 = *(const float4*)(Bbase + (size_t)(k0 + 8) * 4096);
    __syncthreads();
    *(float4*)&As[lr][lc] = a0;
    *(float4*)&As[lr + 8][lc] = a1;
    *(float4*)&Bs[lr][lc] = b0;
    *(float4*)&Bs[lr + 8][lc] = b1;
    __syncthreads();
#pragma unroll
    for (int kk = 0; kk < 16; ++kk) {
      float av[8], bv[8];
      *(float4*)&av[0] = *(const float4*)&As[kk][ty * 8];
      *(float4*)&av[4] = *(const float4*)&As[kk][ty * 8 + 4];
      *(float4*)&bv[0] = *(const float4*)&Bs[kk][tx * 8];
      *(float4*)&bv[4] = *(const float4*)&Bs[kk][tx * 8 + 4];
#pragma unroll
      for (int i = 0; i < 8; ++i)
#pragma unroll
        for (int j = 0; j < 8; ++j) acc[i][j] = fmaf(av[i], bv[j], acc[i][j]);
    }
  }
#pragma unroll
  for (int i = 0; i < 8; ++i) {
    float* row = X + (size_t)(u0 + ty * 8 + i) * 4096 + v0 + tx * 8;
    float4 c0 = {acc[i][0], acc[i][1], acc[i][2], acc[i][3]};
    float4 c1 = {acc[i][4], acc[i][5], acc[i][6], acc[i][7]};
    *(float4*)row = c0;
    *(float4*)(row + 4) = c1;
  }
}

// ---------------------------------------------------------------------------
// Kernel 3: fused 9-tap diagonal stencil + partial argmax over ref positions.
// corr(p,q) = sum_t X[u_base*4096 + v_base + t*4097], t in {0,1,2,64,65,66,128,129,130}
__global__ void argmax_partial(const float* __restrict__ X,
                               float* __restrict__ pval, int* __restrict__ pidx) {
  int qq = blockIdx.x * 256 + threadIdx.x;
  int qv = qq < 3844 ? qq : 3843;
  int v = (qv / 62) * 64 + (qv % 62);
  const int pi = blockIdx.y;   // chunk = one ref row pi, pj = 0..61
  const float* Xrow = X + (size_t)(pi * 64) * 4096 + v;
  float best = -3.0e38f;
  int bi = 0;
  for (int pj = 0; pj < 62; ++pj) {
    const float* base = Xrow + (size_t)pj * 4096;
    float s = 0.f;
#pragma unroll
    for (int di = 0; di < 3; ++di)
#pragma unroll
      for (int dj = 0; dj < 3; ++dj) s += base[(di * 64 + dj) * 4097];
    if (s > best) { best = s; bi = pi * 62 + pj; }   // strict > : first max wins
  }
  if (qq < 3844) {
    pval[(size_t)blockIdx.y * 3844 + qq] = best;
    pidx[(size_t)blockIdx.y * 3844 + qq] = bi;
  }
}

// ---------------------------------------------------------------------------
// Kernel 4: reduce the 62 chunks (ascending p order; strict > keeps first max).
__global__ void argmax_reduce(const float* __restrict__ pval, const int* __restrict__ pidx,
                              int* __restrict__ fidx) {
  int qq = blockIdx.x * 256 + threadIdx.x;
  if (qq >= 3844) return;
  float best = -3.0e38f;
  int bi = 0;
  for (int c = 0; c < 62; ++c) {
    float vv = pval[(size_t)c * 3844 + qq];
    if (vv > best) { best = vv; bi = pidx[(size_t)c * 3844 + qq]; }
  }
  fidx[qq] = bi;
}

// ---------------------------------------------------------------------------
// Kernel 5: index -> flow, pad to 64x64, 9 shifted copies. out (2,9,64,64,2).
__global__ void flow_kernel(const int* __restrict__ fidx, float* __restrict__ out) {
  int t = blockIdx.x * 256 + threadIdx.x;
  if (t >= 147456) return;
  int comp = t & 1;
  int w = (t >> 1) & 63;
  int h = (t >> 7) & 63;
  int s = (t >> 13) % 9;
  int b = t / 73728;
  int i = s / 3, j = s % 3;
  int y = h - i, x = w - j;
  float val = 0.f;
  if (y >= 0 && x >= 0 && y < 62 && x < 62) {
    int idx = fidx[b * 3844 + y * 62 + x];
    val = (comp == 0) ? (float)(idx % 62) - (float)x : (float)(idx / 62) - (float)y;
  }
  out[t] = val;
}

// ---------------------------------------------------------------------------
extern "C" void kernel_launch(void* const* d_in, const int* in_sizes, int n_in,
                              void* d_out, int out_size, void* d_ws, size_t ws_size,
                              hipStream_t stream) {
  const float* df1 = (const float*)d_in[0];  // dense_features1 -> input (B / columns)
  const float* df2 = (const float*)d_in[1];  // dense_features2 -> ref   (A / rows)
  float* out = (float*)d_out;

  float* ws = (float*)d_ws;
  float* Bn = ws;                       // 2*256*4096  (per-batch stride 1048576)
  float* An = Bn + 2097152;             // 2*256*4096
  float* X  = An + 2097152;             // 4096*4096
  float* pval = X + 16777216;           // 62*3844
  int* pidx = (int*)(pval + 238328);    // 62*3844
  int* fidx = pidx + 238328;            // 2*3844

  norm_kernel<<<64, 256, 0, stream>>>(df1, df2, Bn, An);

  const size_t BATCH_STRIDE = 1048576;  // 256*4096 floats per batch  (was the bug: 2097152)
  for (int b = 0; b < 2; ++b) {
    gemm128<<<dim3(32, 32), 256, 0, stream>>>(An + (size_t)b * BATCH_STRIDE,
                                              Bn + (size_t)b * BATCH_STRIDE, X);
    argmax_partial<<<dim3(16, 62), 256, 0, stream>>>(X, pval, pidx);
    argmax_reduce<<<16, 256, 0, stream>>>(pval, pidx, fidx + b * 3844);
  }

  flow_kernel<<<576, 256, 0, stream>>>(fidx, out);
}

// Round 3
// 240.969 us; speedup vs baseline: 1.3635x; 1.3635x over previous
//
#include <hip/hip_runtime.h>

// B=2, C=256, H=W=64, P=3 -> Hp=Wp=62, Np=3844. X grid 4096x4096 fp32 (64 MiB).
// X = A^T B via f16 MFMA with hi/lo split:
//   a = hi + 2^-12 * lo',  hi = fp16(a), lo' = fp16(4096*(a-hi))
//   K-stacked segments: A = [hi | lo' | hi], B = [lo' | hi | hi]  (K=768)
//   acc *= 2^-12 after k=512 (cross terms), then add hi*hi at scale 1.

typedef _Float16 half8 __attribute__((ext_vector_type(8)));
typedef float floatx4 __attribute__((ext_vector_type(4)));
typedef __attribute__((address_space(1))) const void gv_t;
typedef __attribute__((address_space(3))) void lv_t;

// ---------------------------------------------------------------------------
// prep: per-pixel L2 norm + fp16 hi/lo split + transpose to [pix][768] packed
// layout with slot-level XOR pre-swizzle (slot ^= (pix>>1)&3 within each BK=32
// row quarter) so the GEMM can stage linearly with global_load_lds and apply
// the same XOR on its LDS fragment reads.
__global__ void prep_kernel(const float* __restrict__ df1, const float* __restrict__ df2,
                            _Float16* __restrict__ Apack, _Float16* __restrict__ Bpack) {
  int t = blockIdx.x * 256 + threadIdx.x;   // 0..16383
  int pix = t & 4095;
  int bm = t >> 12;
  int b = bm >> 1, m = bm & 1;              // m=0: df1 -> Bpack, m=1: df2 -> Apack
  const float* src = (m ? df2 : df1) + (size_t)b * 1048576 + pix;

  float ss = 0.f;
  for (int c = 0; c < 256; ++c) {
    float v = src[(size_t)c * 4096];
    ss += v * v;
  }
  float sc = 1.f / fmaxf(sqrtf(ss), 1e-12f);

  _Float16* dst = (m ? Apack : Bpack) + (size_t)b * 3145728 + (size_t)pix * 768;
  int swz = (pix >> 1) & 3;

  for (int c0 = 0; c0 < 256; c0 += 8) {
    half8 hi, lo;
#pragma unroll
    for (int j = 0; j < 8; ++j) {
      float v = src[(size_t)(c0 + j) * 4096] * sc;
      _Float16 h = (_Float16)v;
      hi[j] = h;
      lo[j] = (_Float16)(4096.f * (v - (float)h));
    }
    int so = c0 >> 3;                       // octet index 0..31 within a segment
    int s0 = so, s1 = 32 + so, s2 = 64 + so;
    s0 = (s0 & ~3) | ((s0 & 3) ^ swz);
    s1 = (s1 & ~3) | ((s1 & 3) ^ swz);
    s2 = (s2 & ~3) | ((s2 & 3) ^ swz);
    if (m) {  // A = [hi | lo | hi]
      *(half8*)(dst + s0 * 8) = hi;
      *(half8*)(dst + s1 * 8) = lo;
      *(half8*)(dst + s2 * 8) = hi;
    } else {  // B = [lo | hi | hi]
      *(half8*)(dst + s0 * 8) = lo;
      *(half8*)(dst + s1 * 8) = hi;
      *(half8*)(dst + s2 * 8) = hi;
    }
  }
}

// ---------------------------------------------------------------------------
// MFMA GEMM: X[u][v] = sum_k A[u][k] * B[v][k]  (NT: both operands K-contiguous)
// 128x128 tile, 4 waves (2x2), each wave 64x64 = 4x4 fragments of 16x16x32 f16.
__global__ __launch_bounds__(256) void gemm_mfma(const _Float16* __restrict__ A,
                                                 const _Float16* __restrict__ B,
                                                 float* __restrict__ X) {
  __shared__ _Float16 As[128 * 32];
  __shared__ _Float16 Bs[128 * 32];

  int bid = blockIdx.x;                     // 1024 blocks; XCD-aware swizzle (1024%8==0)
  int swb = (bid & 7) * 128 + (bid >> 3);
  int bx = swb & 31, by = swb >> 5;
  const int u0 = by << 7, v0 = bx << 7;

  const int tid = threadIdx.x, lane = tid & 63, wid = tid >> 6;
  const int wr = wid >> 1, wc = wid & 1;

  floatx4 acc[4][4];
#pragma unroll
  for (int i = 0; i < 4; ++i)
#pragma unroll
    for (int j = 0; j < 4; ++j) acc[i][j] = (floatx4){0.f, 0.f, 0.f, 0.f};

  // fragment read offsets (elements); swizzle on k-slot: slot' = slot ^ ((row>>1)&3)
  const int frow = lane & 15;               // row-within-16 fragment
  const int fswz = (lane >> 1) & 3;         // == ((row)>>1)&3 since 16|64 offsets keep bits1-2
  const int fslot = ((lane >> 4) ^ fswz);   // swizzled 16B slot 0..3

  for (int ks = 0; ks < 24; ++ks) {
    const int kbase = ks * 32;
    // ---- stage A,B tiles (linear: packed data is pre-swizzled) ----
#pragma unroll
    for (int i = 0; i < 2; ++i) {
      int ci = wid * 2 + i;                 // 0..7
      int chunk = ci * 64 + lane;           // 0..511
      int row = chunk >> 2, sl = chunk & 3;
      __builtin_amdgcn_global_load_lds(
          (gv_t*)(A + (size_t)(u0 + row) * 768 + kbase + sl * 8),
          (lv_t*)(As + ci * 512), 16, 0, 0);
      __builtin_amdgcn_global_load_lds(
          (gv_t*)(B + (size_t)(v0 + row) * 768 + kbase + sl * 8),
          (lv_t*)(Bs + ci * 512), 16, 0, 0);
    }
    __syncthreads();

    // ---- fragments + MFMA ----
    half8 a[4], b[4];
#pragma unroll
    for (int mr = 0; mr < 4; ++mr) {
      int row = wr * 64 + mr * 16 + frow;
      a[mr] = *(const half8*)(As + row * 32 + fslot * 8);
    }
#pragma unroll
    for (int nr = 0; nr < 4; ++nr) {
      int row = wc * 64 + nr * 16 + frow;
      b[nr] = *(const half8*)(Bs + row * 32 + fslot * 8);
    }
#pragma unroll
    for (int mr = 0; mr < 4; ++mr)
#pragma unroll
      for (int nr = 0; nr < 4; ++nr)
        acc[mr][nr] = __builtin_amdgcn_mfma_f32_16x16x32_f16(a[mr], b[nr], acc[mr][nr], 0, 0, 0);
    __syncthreads();

    if (ks == 15) {  // cross terms (k<512) done -> scale by 2^-12 before hi*hi
#pragma unroll
      for (int i = 0; i < 4; ++i)
#pragma unroll
        for (int j = 0; j < 4; ++j)
#pragma unroll
          for (int r = 0; r < 4; ++r) acc[i][j][r] *= 0.000244140625f;
    }
  }

  // ---- epilogue: C/D layout col=lane&15, row=4*(lane>>4)+r ----
#pragma unroll
  for (int mr = 0; mr < 4; ++mr) {
    int u = u0 + wr * 64 + mr * 16 + (lane >> 4) * 4;
#pragma unroll
    for (int nr = 0; nr < 4; ++nr) {
      int v = v0 + wc * 64 + nr * 16 + (lane & 15);
      float* p = X + (size_t)u * 4096 + v;
#pragma unroll
      for (int r = 0; r < 4; ++r) p[(size_t)r * 4096] = acc[mr][nr][r];
    }
  }
}

// ---------------------------------------------------------------------------
// fused 9-tap diagonal stencil + partial argmax over ref positions.
__global__ void argmax_partial(const float* __restrict__ X,
                               float* __restrict__ pval, int* __restrict__ pidx) {
  int qq = blockIdx.x * 256 + threadIdx.x;
  int qv = qq < 3844 ? qq : 3843;
  int v = (qv / 62) * 64 + (qv % 62);
  const int pi = blockIdx.y;
  const float* Xrow = X + (size_t)(pi * 64) * 4096 + v;
  float best = -3.0e38f;
  int bi = 0;
  for (int pj = 0; pj < 62; ++pj) {
    const float* base = Xrow + (size_t)pj * 4096;
    float s = 0.f;
#pragma unroll
    for (int di = 0; di < 3; ++di)
#pragma unroll
      for (int dj = 0; dj < 3; ++dj) s += base[(di * 64 + dj) * 4097];
    if (s > best) { best = s; bi = pi * 62 + pj; }
  }
  if (qq < 3844) {
    pval[(size_t)blockIdx.y * 3844 + qq] = best;
    pidx[(size_t)blockIdx.y * 3844 + qq] = bi;
  }
}

__global__ void argmax_reduce(const float* __restrict__ pval, const int* __restrict__ pidx,
                              int* __restrict__ fidx) {
  int qq = blockIdx.x * 256 + threadIdx.x;
  if (qq >= 3844) return;
  float best = -3.0e38f;
  int bi = 0;
  for (int c = 0; c < 62; ++c) {
    float vv = pval[(size_t)c * 3844 + qq];
    if (vv > best) { best = vv; bi = pidx[(size_t)c * 3844 + qq]; }
  }
  fidx[qq] = bi;
}

// ---------------------------------------------------------------------------
__global__ void flow_kernel(const int* __restrict__ fidx, float* __restrict__ out) {
  int t = blockIdx.x * 256 + threadIdx.x;
  if (t >= 147456) return;
  int comp = t & 1;
  int w = (t >> 1) & 63;
  int h = (t >> 7) & 63;
  int s = (t >> 13) % 9;
  int b = t / 73728;
  int i = s / 3, j = s % 3;
  int y = h - i, x = w - j;
  float val = 0.f;
  if (y >= 0 && x >= 0 && y < 62 && x < 62) {
    int idx = fidx[b * 3844 + y * 62 + x];
    val = (comp == 0) ? (float)(idx % 62) - (float)x : (float)(idx / 62) - (float)y;
  }
  out[t] = val;
}

// ---------------------------------------------------------------------------
extern "C" void kernel_launch(void* const* d_in, const int* in_sizes, int n_in,
                              void* d_out, int out_size, void* d_ws, size_t ws_size,
                              hipStream_t stream) {
  const float* df1 = (const float*)d_in[0];  // input  -> B operand (columns v)
  const float* df2 = (const float*)d_in[1];  // ref    -> A operand (rows u)
  float* out = (float*)d_out;

  char* ws = (char*)d_ws;
  _Float16* Apack = (_Float16*)ws;                       // 2*4096*768 f16 = 12.6 MB
  _Float16* Bpack = (_Float16*)(ws + 12582912);          // 12.6 MB
  float* X = (float*)(ws + 25165824);                    // 64 MiB
  float* pval = (float*)(ws + 25165824 + 67108864);      // 62*3844 f32
  int* pidx = (int*)((char*)pval + 953312);
  int* fidx = (int*)((char*)pidx + 953312);              // 2*3844 int

  prep_kernel<<<64, 256, 0, stream>>>(df1, df2, Apack, Bpack);

  for (int b = 0; b < 2; ++b) {
    gemm_mfma<<<1024, 256, 0, stream>>>(Apack + (size_t)b * 3145728,
                                        Bpack + (size_t)b * 3145728, X);
    argmax_partial<<<dim3(16, 62), 256, 0, stream>>>(X, pval, pidx);
    argmax_reduce<<<16, 256, 0, stream>>>(pval, pidx, fidx + b * 3844);
  }

  flow_kernel<<<576, 256, 0, stream>>>(fidx, out);
}

// Round 4
// 224.247 us; speedup vs baseline: 1.4652x; 1.0746x over previous
//
#include <hip/hip_runtime.h>

// B=2, C=256, H=W=64, P=3 -> Hp=Wp=62, Np=3844.
// X = A^T B via f16 MFMA hi/lo split (K=768), stored TILE-MAJOR:
//   tile (a,c) = X[u=a*64+b][v=c*64+d] at offset (a*64+c)*4096 + b*64 + d.
// corr(p,q) = sum_{di,dj} X4[pi+di][pj+dj][qi+di][qj+dj] -> block (pi,qi)
// stages the 3 diagonal tiles and does the 9-tap + argmax from LDS.

typedef _Float16 half8 __attribute__((ext_vector_type(8)));
typedef float floatx4 __attribute__((ext_vector_type(4)));
typedef __attribute__((address_space(1))) const void gv_t;
typedef __attribute__((address_space(3))) void lv_t;

// ---------------------------------------------------------------------------
// prep: per-pixel L2 norm + fp16 hi/lo split + pack to [pix][768] with slot
// XOR pre-swizzle. 256 blocks x 64 threads (thread = one (b,map,pixel)).
__global__ void prep_kernel(const float* __restrict__ df1, const float* __restrict__ df2,
                            _Float16* __restrict__ Apack, _Float16* __restrict__ Bpack) {
  int t = blockIdx.x * 64 + threadIdx.x;    // 0..16383
  int pix = t & 4095;
  int bm = t >> 12;
  int b = bm >> 1, m = bm & 1;              // m=0: df1 -> Bpack, m=1: df2 -> Apack
  const float* src = (m ? df2 : df1) + (size_t)b * 1048576 + pix;

  float ss = 0.f;
  for (int c = 0; c < 256; ++c) {
    float v = src[(size_t)c * 4096];
    ss += v * v;
  }
  float sc = 1.f / fmaxf(sqrtf(ss), 1e-12f);

  _Float16* dst = (m ? Apack : Bpack) + (size_t)b * 3145728 + (size_t)pix * 768;
  int swz = (pix >> 1) & 3;

  for (int c0 = 0; c0 < 256; c0 += 8) {
    half8 hi, lo;
#pragma unroll
    for (int j = 0; j < 8; ++j) {
      float v = src[(size_t)(c0 + j) * 4096] * sc;
      _Float16 h = (_Float16)v;
      hi[j] = h;
      lo[j] = (_Float16)(4096.f * (v - (float)h));
    }
    int so = c0 >> 3;
    int s0 = so, s1 = 32 + so, s2 = 64 + so;
    s0 = (s0 & ~3) | ((s0 & 3) ^ swz);
    s1 = (s1 & ~3) | ((s1 & 3) ^ swz);
    s2 = (s2 & ~3) | ((s2 & 3) ^ swz);
    if (m) {  // A = [hi | lo | hi]
      *(half8*)(dst + s0 * 8) = hi;
      *(half8*)(dst + s1 * 8) = lo;
      *(half8*)(dst + s2 * 8) = hi;
    } else {  // B = [lo | hi | hi]
      *(half8*)(dst + s0 * 8) = lo;
      *(half8*)(dst + s1 * 8) = hi;
      *(half8*)(dst + s2 * 8) = hi;
    }
  }
}

// ---------------------------------------------------------------------------
// MFMA GEMM: X[u][v] = sum_k A[u][k]*B[v][k]; 128x128 tile, 4 waves, 4x4 frags.
// Epilogue writes TILE-MAJOR X.
__global__ __launch_bounds__(256) void gemm_mfma(const _Float16* __restrict__ A,
                                                 const _Float16* __restrict__ B,
                                                 float* __restrict__ X) {
  __shared__ _Float16 As[128 * 32];
  __shared__ _Float16 Bs[128 * 32];

  int bid = blockIdx.x;                     // 1024 blocks; XCD swizzle (1024%8==0)
  int swb = (bid & 7) * 128 + (bid >> 3);
  int bx = swb & 31, by = swb >> 5;
  const int u0 = by << 7, v0 = bx << 7;

  const int tid = threadIdx.x, lane = tid & 63, wid = tid >> 6;
  const int wr = wid >> 1, wc = wid & 1;

  floatx4 acc[4][4];
#pragma unroll
  for (int i = 0; i < 4; ++i)
#pragma unroll
    for (int j = 0; j < 4; ++j) acc[i][j] = (floatx4){0.f, 0.f, 0.f, 0.f};

  const int frow = lane & 15;
  const int fswz = (lane >> 1) & 3;
  const int fslot = ((lane >> 4) ^ fswz);

  for (int ks = 0; ks < 24; ++ks) {
    const int kbase = ks * 32;
#pragma unroll
    for (int i = 0; i < 2; ++i) {
      int ci = wid * 2 + i;
      int chunk = ci * 64 + lane;
      int row = chunk >> 2, sl = chunk & 3;
      __builtin_amdgcn_global_load_lds(
          (gv_t*)(A + (size_t)(u0 + row) * 768 + kbase + sl * 8),
          (lv_t*)(As + ci * 512), 16, 0, 0);
      __builtin_amdgcn_global_load_lds(
          (gv_t*)(B + (size_t)(v0 + row) * 768 + kbase + sl * 8),
          (lv_t*)(Bs + ci * 512), 16, 0, 0);
    }
    __syncthreads();

    half8 a[4], b[4];
#pragma unroll
    for (int mr = 0; mr < 4; ++mr) {
      int row = wr * 64 + mr * 16 + frow;
      a[mr] = *(const half8*)(As + row * 32 + fslot * 8);
    }
#pragma unroll
    for (int nr = 0; nr < 4; ++nr) {
      int row = wc * 64 + nr * 16 + frow;
      b[nr] = *(const half8*)(Bs + row * 32 + fslot * 8);
    }
#pragma unroll
    for (int mr = 0; mr < 4; ++mr)
#pragma unroll
      for (int nr = 0; nr < 4; ++nr)
        acc[mr][nr] = __builtin_amdgcn_mfma_f32_16x16x32_f16(a[mr], b[nr], acc[mr][nr], 0, 0, 0);
    __syncthreads();

    if (ks == 15) {  // cross terms done -> scale by 2^-12 before hi*hi segment
#pragma unroll
      for (int i = 0; i < 4; ++i)
#pragma unroll
        for (int j = 0; j < 4; ++j)
#pragma unroll
          for (int r = 0; r < 4; ++r) acc[i][j][r] *= 0.000244140625f;
    }
  }

  // epilogue: tile-major store. C/D layout: col=lane&15, row=4*(lane>>4)+r.
#pragma unroll
  for (int mr = 0; mr < 4; ++mr) {
    int u = u0 + wr * 64 + mr * 16 + (lane >> 4) * 4;
    int a4 = u >> 6, ub = u & 63;           // a4 constant over r (ub+3 <= 63)
#pragma unroll
    for (int nr = 0; nr < 4; ++nr) {
      int v = v0 + wc * 64 + nr * 16 + (lane & 15);
      int c4 = v >> 6, vb = v & 63;
      float* p = X + ((size_t)(a4 * 64 + c4) << 12) + (ub << 6) + vb;
#pragma unroll
      for (int r = 0; r < 4; ++r) p[r * 64] = acc[mr][nr][r];
    }
  }
}

// ---------------------------------------------------------------------------
// corr_argmax: block (qi,pi) stages 3 diagonal 64x64 tiles, computes the
// 9-tap sums for all (pj,qj) in 62x62, partial-argmax over pj (first-max).
__global__ __launch_bounds__(256) void corr_argmax(const float* __restrict__ X,
                                                   float* __restrict__ pval,
                                                   int* __restrict__ pidx) {
  __shared__ float T[3][4096];   // 3 tiles, linear (global_load_lds dest)
  __shared__ float mv[16][64];
  __shared__ int mi[16][64];
  const int qi = blockIdx.x, pi = blockIdx.y;
  const int t = threadIdx.x, lane = t & 63, wid = t >> 6;

  // stage 3 tiles: 48 chunks of 1KB (64 lanes x 16B), linear LDS dest
#pragma unroll
  for (int di = 0; di < 3; ++di) {
    const float* src = X + ((size_t)((pi + di) * 64 + (qi + di)) << 12);
    for (int k = wid; k < 16; k += 4) {
      __builtin_amdgcn_global_load_lds((gv_t*)(src + k * 256 + lane * 4),
                                       (lv_t*)(&T[di][k * 256]), 16, 0, 0);
    }
  }
  __syncthreads();

  const int pg = t >> 4, qg = t & 15;
  const int pj0 = pg * 4, qj0 = qg * 4;

  float acc[4][4];
#pragma unroll
  for (int i = 0; i < 4; ++i)
#pragma unroll
    for (int j = 0; j < 4; ++j) acc[i][j] = 0.f;

#pragma unroll
  for (int di = 0; di < 3; ++di) {
    float v[6][8];
#pragma unroll
    for (int r = 0; r < 6; ++r) {
      int rr = pj0 + r; if (rr > 63) rr = 63;   // clamped rows feed only invalid pj
      *(float4*)&v[r][0] = *(const float4*)&T[di][rr * 64 + qj0];
      *(float4*)&v[r][4] = *(const float4*)&T[di][rr * 64 + qj0 + 4];  // may read past row: feeds only invalid qj
    }
#pragma unroll
    for (int i = 0; i < 4; ++i)
#pragma unroll
      for (int j = 0; j < 4; ++j)
        acc[i][j] += v[i][j] + v[i + 1][j + 1] + v[i + 2][j + 2];
  }

  // per-thread argmax over its 4 pj (ascending, strict >) for each of 4 qj
  float bv[4]; int bp[4];
#pragma unroll
  for (int j = 0; j < 4; ++j) { bv[j] = -3.0e38f; bp[j] = 0; }
#pragma unroll
  for (int i = 0; i < 4; ++i) {
    bool pvalid = (pj0 + i) < 62;
#pragma unroll
    for (int j = 0; j < 4; ++j) {
      float val = pvalid ? acc[i][j] : -3.0e38f;
      if (val > bv[j]) { bv[j] = val; bp[j] = pj0 + i; }
    }
  }
#pragma unroll
  for (int j = 0; j < 4; ++j) { mv[pg][qj0 + j] = bv[j]; mi[pg][qj0 + j] = bp[j]; }
  __syncthreads();

  // merge 16 pj-groups (ascending g = ascending pj -> first-max preserved)
  if (t < 62) {
    float best = -3.0e38f; int bpj = 0;
    for (int g = 0; g < 16; ++g) {
      float vv = mv[g][t];
      if (vv > best) { best = vv; bpj = mi[g][t]; }
    }
    int q = qi * 62 + t;
    pval[(size_t)pi * 3844 + q] = best;
    pidx[(size_t)pi * 3844 + q] = pi * 62 + bpj;
  }
}

// ---------------------------------------------------------------------------
__global__ void argmax_reduce(const float* __restrict__ pval, const int* __restrict__ pidx,
                              int* __restrict__ fidx) {
  int qq = blockIdx.x * 256 + threadIdx.x;
  if (qq >= 3844) return;
  float best = -3.0e38f;
  int bi = 0;
  for (int c = 0; c < 62; ++c) {
    float vv = pval[(size_t)c * 3844 + qq];
    if (vv > best) { best = vv; bi = pidx[(size_t)c * 3844 + qq]; }
  }
  fidx[qq] = bi;
}

// ---------------------------------------------------------------------------
__global__ void flow_kernel(const int* __restrict__ fidx, float* __restrict__ out) {
  int t = blockIdx.x * 256 + threadIdx.x;
  if (t >= 147456) return;
  int comp = t & 1;
  int w = (t >> 1) & 63;
  int h = (t >> 7) & 63;
  int s = (t >> 13) % 9;
  int b = t / 73728;
  int i = s / 3, j = s % 3;
  int y = h - i, x = w - j;
  float val = 0.f;
  if (y >= 0 && x >= 0 && y < 62 && x < 62) {
    int idx = fidx[b * 3844 + y * 62 + x];
    val = (comp == 0) ? (float)(idx % 62) - (float)x : (float)(idx / 62) - (float)y;
  }
  out[t] = val;
}

// ---------------------------------------------------------------------------
extern "C" void kernel_launch(void* const* d_in, const int* in_sizes, int n_in,
                              void* d_out, int out_size, void* d_ws, size_t ws_size,
                              hipStream_t stream) {
  const float* df1 = (const float*)d_in[0];  // input  -> B operand (columns v)
  const float* df2 = (const float*)d_in[1];  // ref    -> A operand (rows u)
  float* out = (float*)d_out;

  char* ws = (char*)d_ws;
  _Float16* Apack = (_Float16*)ws;                       // 2*4096*768 f16
  _Float16* Bpack = (_Float16*)(ws + 12582912);
  float* X = (float*)(ws + 25165824);                    // 64 MiB tile-major
  float* pval = (float*)(ws + 25165824 + 67108864);      // 62*3844 f32
  int* pidx = (int*)((char*)pval + 953312);
  int* fidx = (int*)((char*)pidx + 953312);              // 2*3844 int

  prep_kernel<<<256, 64, 0, stream>>>(df1, df2, Apack, Bpack);

  const size_t BATCH_STRIDE = 3145728;  // f16 elements per batch per operand
  for (int b = 0; b < 2; ++b) {
    gemm_mfma<<<1024, 256, 0, stream>>>(Apack + (size_t)b * BATCH_STRIDE,
                                        Bpack + (size_t)b * BATCH_STRIDE, X);
    corr_argmax<<<dim3(62, 62), 256, 0, stream>>>(X, pval, pidx);
    argmax_reduce<<<16, 256, 0, stream>>>(pval, pidx, fidx + b * 3844);
  }

  flow_kernel<<<576, 256, 0, stream>>>(fidx, out);
}

// Round 5
// 200.617 us; speedup vs baseline: 1.6377x; 1.1178x over previous
//
#include <hip/hip_runtime.h>

// B=2, C=256, H=W=64, P=3 -> Hp=Wp=62, Np=3844.
// X = A^T B via f16 MFMA hi/lo split (K=768), stored TILE-MAJOR.
// GEMM: 128x128 tile, BK=64, LDS double-buffer, counted vmcnt(8) pipeline
// (never vmcnt(0) in steady state), raw s_barrier (no __syncthreads drain).
// LDS rows are 64 f16 = 8 slots of 16B; slot XOR-swizzled by (row&7),
// pre-applied at pack time so global_load_lds writes stay linear.

typedef _Float16 half8 __attribute__((ext_vector_type(8)));
typedef float floatx4 __attribute__((ext_vector_type(4)));
typedef __attribute__((address_space(1))) const void gv_t;
typedef __attribute__((address_space(3))) void lv_t;

// ---------------------------------------------------------------------------
// prep: per-pixel L2 norm + f16 hi/lo split + pack [pix][768] with 8-slot XOR
// pre-swizzle (slot ^= pix&7 within each 64-f16 block). 2 threads per pixel.
__global__ void prep_kernel(const float* __restrict__ df1, const float* __restrict__ df2,
                            _Float16* __restrict__ Apack, _Float16* __restrict__ Bpack) {
  __shared__ float red[128];
  const int tid = threadIdx.x, half = tid >> 6, lane = tid & 63;
  int g = blockIdx.x * 64 + lane;           // pixel-task 0..16383
  int pix = g & 4095;
  int bm = g >> 12;
  int b = bm >> 1, m = bm & 1;              // m=0: df1 -> Bpack, m=1: df2 -> Apack
  const float* src = (m ? df2 : df1) + (size_t)b * 1048576 + pix;

  float ss = 0.f;
  for (int c = half * 128; c < half * 128 + 128; ++c) {
    float v = src[(size_t)c * 4096];
    ss += v * v;
  }
  red[tid] = ss;
  __syncthreads();
  float tot = red[lane] + red[lane + 64];
  float sc = 1.f / fmaxf(sqrtf(tot), 1e-12f);

  _Float16* dst = (m ? Apack : Bpack) + (size_t)b * 3145728 + (size_t)pix * 768;
  const int swz = pix & 7;

  for (int c0 = half * 128; c0 < half * 128 + 128; c0 += 8) {
    half8 hi, lo;
#pragma unroll
    for (int j = 0; j < 8; ++j) {
      float v = src[(size_t)(c0 + j) * 4096] * sc;
      _Float16 h = (_Float16)v;
      hi[j] = h;
      lo[j] = (_Float16)(4096.f * (v - (float)h));
    }
    int o = c0 >> 3;                        // octet 0..31 within a 256-f16 segment
    int blk = o >> 3, sl = (o & 7) ^ swz;   // 64-f16 block, swizzled 16B slot
    // segment s lives at blocks s*4 .. s*4+3
    int off0 = (0 * 4 + blk) * 64 + sl * 8;
    int off1 = (1 * 4 + blk) * 64 + sl * 8;
    int off2 = (2 * 4 + blk) * 64 + sl * 8;
    if (m) {  // A = [hi | lo | hi]
      *(half8*)(dst + off0) = hi;
      *(half8*)(dst + off1) = lo;
      *(half8*)(dst + off2) = hi;
    } else {  // B = [lo | hi | hi]
      *(half8*)(dst + off0) = lo;
      *(half8*)(dst + off1) = hi;
      *(half8*)(dst + off2) = hi;
    }
  }
}

// ---------------------------------------------------------------------------
// MFMA GEMM with counted-vmcnt double-buffer pipeline. Tile-major epilogue.
__global__ __launch_bounds__(256) void gemm_mfma(const _Float16* __restrict__ A,
                                                 const _Float16* __restrict__ B,
                                                 float* __restrict__ X) {
  __shared__ _Float16 As[16384];            // 2 buffers x 128 rows x 64 f16
  __shared__ _Float16 Bs[16384];

  int bid = blockIdx.x;                     // 1024 blocks; XCD swizzle (1024%8==0)
  int swb = (bid & 7) * 128 + (bid >> 3);
  int bx = swb & 31, by = swb >> 5;
  const int u0 = by << 7, v0 = bx << 7;

  const int tid = threadIdx.x, lane = tid & 63, wid = tid >> 6;
  const int wr = wid >> 1, wc = wid & 1;

  floatx4 acc[4][4];
#pragma unroll
  for (int i = 0; i < 4; ++i)
#pragma unroll
    for (int j = 0; j < 4; ++j) acc[i][j] = (floatx4){0.f, 0.f, 0.f, 0.f};

  const _Float16* Abase = A + (size_t)u0 * 768;
  const _Float16* Bbase = B + (size_t)v0 * 768;

  // stage one K-tile (8 gload_lds: 4 A + 4 B interleaved). chunk c = i*256+tid:
  // row = c>>3 (0..127), slot = c&7; LDS dest linear (data pre-swizzled).
#define STAGE(kt, buf)                                                          \
  {                                                                             \
    _Pragma("unroll") for (int i = 0; i < 4; ++i) {                             \
      int c = i * 256 + tid;                                                    \
      int row = c >> 3, sl = c & 7;                                             \
      __builtin_amdgcn_global_load_lds(                                         \
          (gv_t*)(Abase + (size_t)row * 768 + (kt) * 64 + sl * 8),              \
          (lv_t*)(As + (buf) * 8192 + c * 8), 16, 0, 0);                        \
      __builtin_amdgcn_global_load_lds(                                         \
          (gv_t*)(Bbase + (size_t)row * 768 + (kt) * 64 + sl * 8),              \
          (lv_t*)(Bs + (buf) * 8192 + c * 8), 16, 0, 0);                        \
    }                                                                           \
  }

  STAGE(0, 0);
  STAGE(1, 1);

  const int frow = lane & 15;               // row within 16-row fragment
  const int fsw = lane & 7;                 // == row&7 for all fragment rows
  const int fhi = lane >> 4;                // 16B sub-slot 0..3

#pragma unroll
  for (int t = 0; t < 12; ++t) {
    // tile t's 8 loads are the oldest outstanding; allow tile t+1 in flight.
    if (t < 11) asm volatile("s_waitcnt vmcnt(8)" ::: "memory");
    else        asm volatile("s_waitcnt vmcnt(0)" ::: "memory");
    __builtin_amdgcn_s_barrier();           // all waves' tile-t loads landed
    __builtin_amdgcn_sched_barrier(0);

    const _Float16* LA = As + (t & 1) * 8192;
    const _Float16* LB = Bs + (t & 1) * 8192;

    half8 bfr[4][2];
#pragma unroll
    for (int nr = 0; nr < 4; ++nr)
#pragma unroll
      for (int kk = 0; kk < 2; ++kk) {
        int row = wc * 64 + nr * 16 + frow;
        int sl = (kk * 4 + fhi) ^ fsw;
        bfr[nr][kk] = *(const half8*)(LB + row * 64 + sl * 8);
      }
#pragma unroll
    for (int mr = 0; mr < 4; ++mr) {
      half8 afr[2];
#pragma unroll
      for (int kk = 0; kk < 2; ++kk) {
        int row = wr * 64 + mr * 16 + frow;
        int sl = (kk * 4 + fhi) ^ fsw;
        afr[kk] = *(const half8*)(LA + row * 64 + sl * 8);
      }
#pragma unroll
      for (int nr = 0; nr < 4; ++nr)
#pragma unroll
        for (int kk = 0; kk < 2; ++kk)
          acc[mr][nr] = __builtin_amdgcn_mfma_f32_16x16x32_f16(afr[kk], bfr[nr][kk],
                                                               acc[mr][nr], 0, 0, 0);
    }

    if (t == 7) {  // cross terms (k<512) done -> scale by 2^-12 before hi*hi
#pragma unroll
      for (int i = 0; i < 4; ++i)
#pragma unroll
        for (int j = 0; j < 4; ++j)
#pragma unroll
          for (int r = 0; r < 4; ++r) acc[i][j][r] *= 0.000244140625f;
    }

    asm volatile("s_waitcnt lgkmcnt(0)" ::: "memory");  // all LDS reads retired
    __builtin_amdgcn_sched_barrier(0);
    __builtin_amdgcn_s_barrier();           // buf (t&1) free for overwrite
    if (t < 10) STAGE(t + 2, t & 1);
  }
#undef STAGE

  // epilogue: tile-major store. C/D layout: col=lane&15, row=4*(lane>>4)+r.
#pragma unroll
  for (int mr = 0; mr < 4; ++mr) {
    int u = u0 + wr * 64 + mr * 16 + (lane >> 4) * 4;
    int a4 = u >> 6, ub = u & 63;
#pragma unroll
    for (int nr = 0; nr < 4; ++nr) {
      int v = v0 + wc * 64 + nr * 16 + (lane & 15);
      int c4 = v >> 6, vb = v & 63;
      float* p = X + ((size_t)(a4 * 64 + c4) << 12) + (ub << 6) + vb;
#pragma unroll
      for (int r = 0; r < 4; ++r) p[r * 64] = acc[mr][nr][r];
    }
  }
}

// ---------------------------------------------------------------------------
// corr_argmax: block (qi,pi) stages 3 diagonal 64x64 tiles, computes the
// 9-tap sums for all (pj,qj) in 62x62, partial-argmax over pj (first-max).
__global__ __launch_bounds__(256) void corr_argmax(const float* __restrict__ X,
                                                   float* __restrict__ pval,
                                                   int* __restrict__ pidx) {
  __shared__ float T[3][4096];
  __shared__ float mv[16][64];
  __shared__ int mi[16][64];
  const int qi = blockIdx.x, pi = blockIdx.y;
  const int t = threadIdx.x, lane = t & 63, wid = t >> 6;

#pragma unroll
  for (int di = 0; di < 3; ++di) {
    const float* src = X + ((size_t)((pi + di) * 64 + (qi + di)) << 12);
    for (int k = wid; k < 16; k += 4) {
      __builtin_amdgcn_global_load_lds((gv_t*)(src + k * 256 + lane * 4),
                                       (lv_t*)(&T[di][k * 256]), 16, 0, 0);
    }
  }
  __syncthreads();

  const int pg = t >> 4, qg = t & 15;
  const int pj0 = pg * 4, qj0 = qg * 4;

  float acc[4][4];
#pragma unroll
  for (int i = 0; i < 4; ++i)
#pragma unroll
    for (int j = 0; j < 4; ++j) acc[i][j] = 0.f;

#pragma unroll
  for (int di = 0; di < 3; ++di) {
    float v[6][8];
#pragma unroll
    for (int r = 0; r < 6; ++r) {
      int rr = pj0 + r; if (rr > 63) rr = 63;
      *(float4*)&v[r][0] = *(const float4*)&T[di][rr * 64 + qj0];
      *(float4*)&v[r][4] = *(const float4*)&T[di][rr * 64 + qj0 + 4];
    }
#pragma unroll
    for (int i = 0; i < 4; ++i)
#pragma unroll
      for (int j = 0; j < 4; ++j)
        acc[i][j] += v[i][j] + v[i + 1][j + 1] + v[i + 2][j + 2];
  }

  float bv[4]; int bp[4];
#pragma unroll
  for (int j = 0; j < 4; ++j) { bv[j] = -3.0e38f; bp[j] = 0; }
#pragma unroll
  for (int i = 0; i < 4; ++i) {
    bool pvalid = (pj0 + i) < 62;
#pragma unroll
    for (int j = 0; j < 4; ++j) {
      float val = pvalid ? acc[i][j] : -3.0e38f;
      if (val > bv[j]) { bv[j] = val; bp[j] = pj0 + i; }
    }
  }
#pragma unroll
  for (int j = 0; j < 4; ++j) { mv[pg][qj0 + j] = bv[j]; mi[pg][qj0 + j] = bp[j]; }
  __syncthreads();

  if (t < 62) {
    float best = -3.0e38f; int bpj = 0;
    for (int g = 0; g < 16; ++g) {
      float vv = mv[g][t];
      if (vv > best) { best = vv; bpj = mi[g][t]; }
    }
    int q = qi * 62 + t;
    pval[(size_t)pi * 3844 + q] = best;
    pidx[(size_t)pi * 3844 + q] = pi * 62 + bpj;
  }
}

// ---------------------------------------------------------------------------
__global__ void argmax_reduce(const float* __restrict__ pval, const int* __restrict__ pidx,
                              int* __restrict__ fidx) {
  int qq = blockIdx.x * 256 + threadIdx.x;
  if (qq >= 3844) return;
  float best = -3.0e38f;
  int bi = 0;
  for (int c = 0; c < 62; ++c) {
    float vv = pval[(size_t)c * 3844 + qq];
    if (vv > best) { best = vv; bi = pidx[(size_t)c * 3844 + qq]; }
  }
  fidx[qq] = bi;
}

// ---------------------------------------------------------------------------
__global__ void flow_kernel(const int* __restrict__ fidx, float* __restrict__ out) {
  int t = blockIdx.x * 256 + threadIdx.x;
  if (t >= 147456) return;
  int comp = t & 1;
  int w = (t >> 1) & 63;
  int h = (t >> 7) & 63;
  int s = (t >> 13) % 9;
  int b = t / 73728;
  int i = s / 3, j = s % 3;
  int y = h - i, x = w - j;
  float val = 0.f;
  if (y >= 0 && x >= 0 && y < 62 && x < 62) {
    int idx = fidx[b * 3844 + y * 62 + x];
    val = (comp == 0) ? (float)(idx % 62) - (float)x : (float)(idx / 62) - (float)y;
  }
  out[t] = val;
}

// ---------------------------------------------------------------------------
extern "C" void kernel_launch(void* const* d_in, const int* in_sizes, int n_in,
                              void* d_out, int out_size, void* d_ws, size_t ws_size,
                              hipStream_t stream) {
  const float* df1 = (const float*)d_in[0];  // input  -> B operand (columns v)
  const float* df2 = (const float*)d_in[1];  // ref    -> A operand (rows u)
  float* out = (float*)d_out;

  char* ws = (char*)d_ws;
  _Float16* Apack = (_Float16*)ws;                       // 2*4096*768 f16
  _Float16* Bpack = (_Float16*)(ws + 12582912);
  float* X = (float*)(ws + 25165824);                    // 64 MiB tile-major
  float* pval = (float*)(ws + 25165824 + 67108864);      // 62*3844 f32
  int* pidx = (int*)((char*)pval + 953312);
  int* fidx = (int*)((char*)pidx + 953312);              // 2*3844 int

  prep_kernel<<<256, 128, 0, stream>>>(df1, df2, Apack, Bpack);

  const size_t BATCH_STRIDE = 3145728;  // f16 elements per batch per operand
  for (int b = 0; b < 2; ++b) {
    gemm_mfma<<<1024, 256, 0, stream>>>(Apack + (size_t)b * BATCH_STRIDE,
                                        Bpack + (size_t)b * BATCH_STRIDE, X);
    corr_argmax<<<dim3(62, 62), 256, 0, stream>>>(X, pval, pidx);
    argmax_reduce<<<16, 256, 0, stream>>>(pval, pidx, fidx + b * 3844);
  }

  flow_kernel<<<576, 256, 0, stream>>>(fidx, out);
}